// Round 7
// baseline (314.076 us; speedup 1.0000x reference)
//
#include <hip/hip_runtime.h>
#include <stdint.h>

#define B_ 8
#define T_ 512
#define M_ 16
#define D_ 128
#define P_ 256
#define H_ 8
#define E_ 32

typedef __attribute__((ext_vector_type(8))) short  short8;
typedef __attribute__((ext_vector_type(4))) short  short4v;
typedef __attribute__((ext_vector_type(4))) float  float4v;
typedef __attribute__((ext_vector_type(2))) unsigned int uint2v;
typedef __attribute__((ext_vector_type(4))) unsigned int uint4v;
typedef __attribute__((ext_vector_type(2))) __bf16 bf16x2;

#define MFMA32(a,b,c) __builtin_amdgcn_mfma_f32_16x16x32_bf16(a,b,c,0,0,0)   // K=32, short8 ops
#define MFMA16(a,b,c) __builtin_amdgcn_mfma_f32_16x16x16bf16_1k(a,b,c,0,0,0) // K=16, short4 ops
#define EXP2F(x) __builtin_amdgcn_exp2f(x)

#define C2 0.2550332772062413f   // log2(e)/sqrt(E)

#if defined(__has_builtin)
# if __has_builtin(__builtin_amdgcn_cvt_pk_bf16_f32)
#  define HAVE_CVT_PK 1
# endif
#endif

static __device__ __forceinline__ unsigned short f2bf(float x){
  unsigned int u = __builtin_bit_cast(unsigned int, x);
  u += 0x7FFFu + ((u >> 16) & 1u);           // RNE
  return (unsigned short)(u >> 16);
}

static __device__ __forceinline__ unsigned int pk2(float a, float b){
#ifdef HAVE_CVT_PK
  bf16x2 h = __builtin_amdgcn_cvt_pk_bf16_f32(a, b);   // v_cvt_pk_bf16_f32 (RNE)
  return __builtin_bit_cast(unsigned int, h);
#else
  return (unsigned int)f2bf(a) | ((unsigned int)f2bf(b) << 16);
#endif
}

static __device__ __forceinline__ short4v pack4(float4v v){
  uint2v u; u.x = pk2(v[0], v[1]); u.y = pk2(v[2], v[3]);
  return __builtin_bit_cast(short4v, u);
}

static __device__ __forceinline__ short8 pack8(float4v a, float4v b){
  uint4v u; u.x = pk2(a[0],a[1]); u.y = pk2(a[2],a[3]);
  u.z = pk2(b[0],b[1]); u.w = pk2(b[2],b[3]);
  return __builtin_bit_cast(short8, u);
}

// ------- kernel 0: WT[z][p][d] bf16 (Wq pre-scaled by C2) + maskf transpose -------
__global__ void prep(const float* __restrict__ Wq, const float* __restrict__ Wk,
                     const float* __restrict__ Wv, const int* __restrict__ mask,
                     uint16_t* __restrict__ WT, float* __restrict__ maskf){
  int idx = blockIdx.x*256 + threadIdx.x;      // 640*256 = 163840
  if (idx < 3*P_*D_){                          // 98304: weight transpose+cast
    int d = idx & (D_-1);
    int p = (idx >> 7) & (P_-1);
    int z = idx >> 15;
    const float* W = (z==0) ? Wq : (z==1) ? Wk : Wv;
    float sc = (z==0) ? C2 : 1.0f;
    WT[idx] = f2bf(W[d*P_ + p] * sc);
  } else {                                     // 65536: mask -> maskf[(b*M+m)*T+s]
    int j = idx - 3*P_*D_;
    int s = j & (T_-1);
    int bm = j >> 9;
    int b = bm >> 4, m = bm & (M_-1);
    maskf[j] = mask[(b*T_ + s)*M_ + m] ? 0.0f : -1e30f;
  }
}

// ---------------- fused QKV + masked attention, one block per (b,m,h) ------
// 16 waves x 32 t-rows. Same inp rows serve as Q's t and K/V's s.
// Proj MFMA C-layout (reg r -> e, lane -> row) IS the A/B operand layout of
// the K=16 MFMA -> Q stays in regs, K -> LDS [s][e] (chunk-swizzled), V ->
// LDS transposed [e][s] (u-swizzled). Mask in LDS, folded into S^T C operand.
// LDS 66 KB -> 2 blocks/CU = 32 waves/CU; VGPR <= 64 for 8 waves/SIMD.
__global__ __launch_bounds__(1024, 8) void attn_fused(
    const float* __restrict__ inp, const uint16_t* __restrict__ WT,
    const float* __restrict__ bq, const float* __restrict__ bk,
    const float* __restrict__ bv, const float* __restrict__ maskf,
    float* __restrict__ out){
  __shared__ __align__(16) uint16_t Kb[T_*E_];   // 32768 B  K[s][e], chunk-swizzled
  __shared__ __align__(16) uint16_t Vt[E_*T_];   // 32768 B  V^T[e][s], u-swizzled
  __shared__ __align__(16) float    maskc[T_];   //  2048 B

  const int bx = blockIdx.x;                // 1024
  const int h = bx >> 7, bm = bx & 127;     // same-bm blocks -> same XCD (bx%8 = bm%8)
  const int b = bm >> 4, m = bm & 15;
  const int tid = threadIdx.x;
  const int wave = tid >> 6, lane = tid & 63;
  const int q4 = lane >> 4, c = lane & 15;
  const int t0 = wave*32;

  if (tid < T_) maskc[tid] = maskf[(size_t)bm*T_ + tid];

  // ---- pack inp rows once: rows t0+tj*16+c, full d ----
  short8 af[2][4];   // [tj][kc]
  for (int tj=0; tj<2; tj++){
    const float* src = inp + (size_t)((b*T_ + t0 + tj*16 + c)*M_ + m)*D_;
    for (int kc=0; kc<4; kc++){
      float4v x0 = *(const float4v*)(src + kc*32 + q4*8);
      float4v x1 = *(const float4v*)(src + kc*32 + q4*8 + 4);
      af[tj][kc] = pack8(x0, x1);
    }
  }

  const uint16_t* WQ = WT                   + (size_t)(h*E_)*D_;
  const uint16_t* WK = WT + (size_t)1*P_*D_ + (size_t)(h*E_)*D_;
  const uint16_t* WV = WT + (size_t)2*P_*D_ + (size_t)(h*E_)*D_;
  float4v zf = {0.f,0.f,0.f,0.f};

  // ---- K projection -> Kb[s][e] (b64 writes, chunk swizzle) ----
  for (int eh=0; eh<2; eh++){
    float4v ka[2]; ka[0]=zf; ka[1]=zf;
    for (int kc=0; kc<4; kc++){
      short8 w = *(const short8*)(WK + (size_t)(eh*16 + c)*D_ + kc*32 + q4*8);
      for (int sj=0; sj<2; sj++) ka[sj] = MFMA32(w, af[sj][kc], ka[sj]);
    }
    float4v bk4 = *(const float4v*)(bk + h*E_ + eh*16 + q4*4);
    for (int sj=0; sj<2; sj++){
      int s = t0 + sj*16 + c;
      short4v kv = pack4(ka[sj] + bk4);
      *(short4v*)(Kb + s*32 + ((4*eh + q4 + s) & 7)*4) = kv;
    }
  }
  // ---- V projection -> Vt[e][s] (scalar b16 transpose writes) ----
  for (int eh=0; eh<2; eh++){
    float4v va[2]; va[0]=zf; va[1]=zf;
    for (int kc=0; kc<4; kc++){
      short8 w = *(const short8*)(WV + (size_t)(eh*16 + c)*D_ + kc*32 + q4*8);
      for (int sj=0; sj<2; sj++) va[sj] = MFMA32(w, af[sj][kc], va[sj]);
    }
    float4v bv4 = *(const float4v*)(bv + h*E_ + eh*16 + q4*4);
    for (int sj=0; sj<2; sj++){
      int s = t0 + sj*16 + c;
      short4v vv = pack4(va[sj] + bv4);
      for (int r=0; r<4; r++){
        int e = eh*16 + q4*4 + r;
        Vt[e*T_ + ((((s>>2) + e) & 127)*4) + (s&3)] = (uint16_t)vv[r];
      }
    }
  }
  // ---- Q projection -> qb regs (C-layout == MFMA16 B-operand layout) ----
  short4v qb[2][2];
  for (int eh=0; eh<2; eh++){
    float4v qa[2]; qa[0]=zf; qa[1]=zf;
    for (int kc=0; kc<4; kc++){
      short8 w = *(const short8*)(WQ + (size_t)(eh*16 + c)*D_ + kc*32 + q4*8);
      for (int tj=0; tj<2; tj++) qa[tj] = MFMA32(w, af[tj][kc], qa[tj]);
    }
    float4v bq4 = *(const float4v*)(bq + h*E_ + eh*16 + q4*4);
    bq4 *= C2;
    for (int tj=0; tj<2; tj++) qb[tj][eh] = pack4(qa[tj] + bq4);
  }
  __syncthreads();

  // ---- s-loop: S^T = K.Q^T (mask as C operand) -> exp2 -> PV ----
  float4v O[2][2], L4[2];
  for (int i=0;i<2;i++){ O[i][0]=zf; O[i][1]=zf; L4[i]=zf; }
  const short one_bf = (short)0x3F80;
  short4v ones; ones[0]=one_bf; ones[1]=one_bf; ones[2]=one_bf; ones[3]=one_bf;

#pragma unroll
  for (int sb=0; sb<16; sb++){
#pragma unroll
    for (int si=0; si<2; si++){
      const int sq = sb*32 + si*16;
      float4v mm = *(const float4v*)(maskc + sq + q4*4);
      const int srow = sq + c;
      short4v kb0 = *(const short4v*)(Kb + srow*32 + ((    q4 + srow) & 7)*4);  // e 0..15
      short4v kb1 = *(const short4v*)(Kb + srow*32 + ((4 + q4 + srow) & 7)*4);  // e 16..31
      const int u = (sq >> 2) + q4;
      short4v vf0 = *(const short4v*)(Vt + (size_t)c*T_      + ((u + c     ) & 127)*4);
      short4v vf1 = *(const short4v*)(Vt + (size_t)(16+c)*T_ + ((u + 16 + c) & 127)*4);
#pragma unroll
      for (int tj=0; tj<2; tj++){
        float4v st = MFMA16(kb1, qb[tj][1], MFMA16(kb0, qb[tj][0], mm));
        float4v p;
        p[0] = EXP2F(st[0]);
        p[1] = EXP2F(st[1]);
        p[2] = EXP2F(st[2]);
        p[3] = EXP2F(st[3]);
        short4v pf = pack4(p);
        O[tj][0] = MFMA16(pf, vf0, O[tj][0]);
        O[tj][1] = MFMA16(pf, vf1, O[tj][1]);
        L4[tj]   = MFMA16(pf, ones, L4[tj]);
      }
    }
  }

  // ---- normalize + direct stores (lane = e, regs = t) ----
  for (int ti=0; ti<2; ti++){
    float4v linv;
    for (int r=0; r<4; r++) linv[r] = __builtin_amdgcn_rcpf(L4[ti][r]);
    for (int ej=0; ej<2; ej++){
      float4v v = O[ti][ej] * linv;
      for (int r=0; r<4; r++){
        int t = t0 + ti*16 + q4*4 + r;
        out[(size_t)((b*T_ + t)*M_ + m)*P_ + h*E_ + ej*16 + c] = v[r];
      }
    }
  }
}

extern "C" void kernel_launch(void* const* d_in, const int* in_sizes, int n_in,
                              void* d_out, int out_size, void* d_ws, size_t ws_size,
                              hipStream_t stream){
  const float* inp = (const float*)d_in[0];
  const int*   msk = (const int*)  d_in[1];
  const float* Wq  = (const float*)d_in[2];
  const float* bq  = (const float*)d_in[3];
  const float* Wk  = (const float*)d_in[4];
  const float* bk  = (const float*)d_in[5];
  const float* Wv  = (const float*)d_in[6];
  const float* bv  = (const float*)d_in[7];
  float* out = (float*)d_out;

  uint16_t* WT    = (uint16_t*)d_ws;                       // 196,608 B
  float*    maskf = (float*)((char*)d_ws + 196608);        // 262,144 B

  prep<<<dim3(640), dim3(256), 0, stream>>>(Wq, Wk, Wv, msk, WT, maskf);
  attn_fused<<<dim3(1024), dim3(1024), 0, stream>>>(inp, WT, bq, bk, bv, maskf, out);
}